// Round 3
// baseline (628.793 us; speedup 1.0000x reference)
//
#include <hip/hip_runtime.h>
#include <hip/hip_bf16.h>
#include <cstdint>
#include <cstddef>

#define NEG_INF (-1.0e9f)

typedef __attribute__((ext_vector_type(8))) short bf16x8;
typedef __attribute__((ext_vector_type(8))) unsigned short u16x8;
typedef __attribute__((ext_vector_type(4))) float f32x4;
typedef __attribute__((ext_vector_type(4))) unsigned int u32x4;

constexpr int BB = 64;     // batch
constexpr int NN = 2048;   // seq len
constexpr int HH = 512;    // h dim
constexpr int DD = 512;    // enc dim (GEMM K)
constexpr int AA = 512;    // attention dim (GEMM N)

__device__ __forceinline__ unsigned short f2bf(float x) {
  unsigned int u = __float_as_uint(x);
  return (unsigned short)((u + 0x8000u) >> 16);
}

__device__ __forceinline__ float fast_rcp(float x) {
#if __has_builtin(__builtin_amdgcn_rcpf)
  return __builtin_amdgcn_rcpf(x);
#else
  return 1.f / x;
#endif
}

__device__ __forceinline__ float fast_tanh(float x) {
  float e = __expf(2.f * fabsf(x));
  float t = 1.f - 2.f * fast_rcp(e + 1.f);
  return copysignf(t, x);
}

// 8 fp32 -> bf16x8 via packed HW cvt (v_cvt_pk_bf16_f32 on gfx950)
__device__ __forceinline__ bf16x8 pack8(const float4& lo, const float4& hi) {
  __hip_bfloat162 a = __float22bfloat162_rn(float2{lo.x, lo.y});
  __hip_bfloat162 b = __float22bfloat162_rn(float2{lo.z, lo.w});
  __hip_bfloat162 c = __float22bfloat162_rn(float2{hi.x, hi.y});
  __hip_bfloat162 d = __float22bfloat162_rn(float2{hi.z, hi.w});
  union { unsigned int w[4]; bf16x8 v; } u;
  __builtin_memcpy(&u.w[0], &a, 4);
  __builtin_memcpy(&u.w[1], &b, 4);
  __builtin_memcpy(&u.w[2], &c, 4);
  __builtin_memcpy(&u.w[3], &d, 4);
  return u.v;
}

// -------- We -> bf16 (512 KB ws) --------
__global__ __launch_bounds__(256)
void we_cast_kernel(const float* __restrict__ We, unsigned short* __restrict__ web) {
  int i = (blockIdx.x * 256 + threadIdx.x) * 8;
  if (i >= AA * DD) return;
  float4 s0 = *(const float4*)(We + i);
  float4 s1 = *(const float4*)(We + i + 4);
  u16x8 p;
  p[0]=f2bf(s0.x); p[1]=f2bf(s0.y); p[2]=f2bf(s0.z); p[3]=f2bf(s0.w);
  p[4]=f2bf(s1.x); p[5]=f2bf(s1.y); p[6]=f2bf(s1.z); p[7]=f2bf(s1.w);
  *(u16x8*)(web + i) = p;
}

// -------- proj_h --------
__global__ __launch_bounds__(256)
void proj_h_kernel(const float* __restrict__ h, const float* __restrict__ Wh,
                   float* __restrict__ ph) {
  __shared__ float hL[HH];
  const int b = blockIdx.x;
  hL[threadIdx.x]       = h[b * HH + threadIdx.x];
  hL[threadIdx.x + 256] = h[b * HH + threadIdx.x + 256];
  __syncthreads();
  const int a = blockIdx.y * 256 + threadIdx.x;
  const float4* wr = (const float4*)(Wh + (size_t)a * HH);
  float acc = 0.f;
  #pragma unroll 4
  for (int j = 0; j < HH / 4; ++j) {
    float4 w = wr[j];
    acc += w.x * hL[4*j] + w.y * hL[4*j+1] + w.z * hL[4*j+2] + w.w * hL[4*j+3];
  }
  ph[b * AA + a] = acc;
}

// -------- fused scores: register-streaming GEMM, zero LDS, zero barriers --------
// Each wave owns 64 rows; per chunk (128 a-cols): acc[4][8] MFMA tiles.
// A-frag: lane loads enc[row0+i*16+c][k0+quad*8 .. +8] fp32 -> cvt_pk -> bf16x8.
// B-frag: lane loads web[col][k0+quad*8 .. +8] directly (16 B).
__global__ __launch_bounds__(256, 2)
void scores_reg(const float* __restrict__ enc, const unsigned short* __restrict__ web,
                const float* __restrict__ ph, const float* __restrict__ vvec,
                float* __restrict__ scores) {
  const int tid  = threadIdx.x;
  const int lane = tid & 63;
  const int wid  = tid >> 6;
  const int c    = lane & 15;
  const int quad = lane >> 4;

  const int r0 = blockIdx.x * 256 + wid * 64;   // wave's global row base (64 rows)
  const int b  = (blockIdx.x * 256) >> 11;      // batch (256 | 2048)

  // A base for this lane's fragment rows: row r0 + i*16 + c, k-offset quad*8
  const float* aBase = enc + ((size_t)(r0 + c)) * DD + quad * 8;

  float srow[16];                                // [i*4+r] per-row score partials
  #pragma unroll
  for (int t = 0; t < 16; ++t) srow[t] = 0.f;

  for (int ch = 0; ch < 4; ++ch) {
    f32x4 acc[4][8];
    #pragma unroll
    for (int i = 0; i < 4; ++i)
      #pragma unroll
      for (int j = 0; j < 8; ++j)
        acc[i][j] = (f32x4){0.f, 0.f, 0.f, 0.f};

    const unsigned short* bBase =
        web + ((size_t)(ch * 128 + c)) * DD + quad * 8;

    #pragma unroll 2
    for (int k0 = 0; k0 < DD; k0 += 32) {
      bf16x8 bfr[8];
      #pragma unroll
      for (int j = 0; j < 8; ++j)
        bfr[j] = *(const bf16x8*)(bBase + (size_t)(j * 16) * DD + k0);
      bf16x8 af[4];
      #pragma unroll
      for (int i = 0; i < 4; ++i) {
        const float* ap = aBase + (size_t)(i * 16) * DD + k0;
        float4 lo = *(const float4*)(ap);
        float4 hi = *(const float4*)(ap + 4);
        af[i] = pack8(lo, hi);
      }
      #pragma unroll
      for (int i = 0; i < 4; ++i)
        #pragma unroll
        for (int j = 0; j < 8; ++j)
          acc[i][j] = __builtin_amdgcn_mfma_f32_16x16x32_bf16(af[i], bfr[j], acc[i][j], 0, 0, 0);
    }

    // epilogue: srow += sum_j v[col]*tanh(acc + ph[col]); C/D: row=quad*4+r, col=c
    float pp[8], vv[8];
    #pragma unroll
    for (int j = 0; j < 8; ++j) {
      int col = ch * 128 + j * 16 + c;
      pp[j] = ph[b * AA + col];
      vv[j] = vvec[col];
    }
    #pragma unroll
    for (int i = 0; i < 4; ++i) {
      #pragma unroll
      for (int r = 0; r < 4; ++r) {
        float p = 0.f;
        #pragma unroll
        for (int j = 0; j < 8; ++j)
          p += vv[j] * fast_tanh(acc[i][j][r] + pp[j]);
        p += __shfl_xor(p, 1, 64);
        p += __shfl_xor(p, 2, 64);
        p += __shfl_xor(p, 4, 64);
        p += __shfl_xor(p, 8, 64);
        srow[i * 4 + r] += p;                    // same value on all 16 c-lanes
      }
    }
  }

  if (c == 0) {
    #pragma unroll
    for (int i = 0; i < 4; ++i)
      #pragma unroll
      for (int r = 0; r < 4; ++r)
        scores[r0 + i * 16 + quad * 4 + r] = srow[i * 4 + r];
  }
}

// -------- masked softmax over N per batch; alpha to d_out --------
__global__ __launch_bounds__(256)
void softmax_kernel(const float* __restrict__ scores, const int* __restrict__ mask,
                    float* __restrict__ alpha) {
  const int b = blockIdx.x, tid = threadIdx.x;
  const int base = b * NN;
  float vals[8];
  float mx = -3.4e38f;
  #pragma unroll
  for (int i = 0; i < 8; ++i) {
    int n = tid + 256 * i;
    float s = scores[base + n];
    if (mask[base + n] == 0) s = NEG_INF;
    vals[i] = s;
    mx = fmaxf(mx, s);
  }
  #pragma unroll
  for (int o = 32; o; o >>= 1) mx = fmaxf(mx, __shfl_xor(mx, o, 64));
  __shared__ float w4[4];
  if ((tid & 63) == 0) w4[tid >> 6] = mx;
  __syncthreads();
  mx = fmaxf(fmaxf(w4[0], w4[1]), fmaxf(w4[2], w4[3]));
  float sum = 0.f;
  #pragma unroll
  for (int i = 0; i < 8; ++i) { vals[i] = __expf(vals[i] - mx); sum += vals[i]; }
  #pragma unroll
  for (int o = 32; o; o >>= 1) sum += __shfl_xor(sum, o, 64);
  __shared__ float s4[4];
  if ((tid & 63) == 0) s4[tid >> 6] = sum;
  __syncthreads();
  sum = s4[0] + s4[1] + s4[2] + s4[3];
  float inv = 1.f / sum;
  #pragma unroll
  for (int i = 0; i < 8; ++i) alpha[base + tid + 256 * i] = vals[i] * inv;
}

// -------- context partials (no atomics) --------
__global__ __launch_bounds__(128)
void context_part(const float* __restrict__ enc, const float* __restrict__ alpha,
                  float* __restrict__ cpart) {
  const int b  = blockIdx.x;
  const int nc = blockIdx.y;     // 16 chunks of 128 n
  const int t  = threadIdx.x;
  __shared__ float aL[128];
  aL[t] = alpha[b * NN + nc * 128 + t];
  __syncthreads();
  const float* ep = enc + ((size_t)b * NN + nc * 128) * DD + t * 4;
  float4 acc = {0.f, 0.f, 0.f, 0.f};
  #pragma unroll 4
  for (int n = 0; n < 128; ++n) {
    float4 e = *(const float4*)(ep + (size_t)n * DD);
    float a = aL[n];
    acc.x += a * e.x; acc.y += a * e.y; acc.z += a * e.z; acc.w += a * e.w;
  }
  *(float4*)(cpart + ((size_t)(b * 16 + nc)) * DD + t * 4) = acc;
}

__global__ __launch_bounds__(256)
void context_reduce(const float* __restrict__ cpart, float* __restrict__ ctx) {
  const int i = blockIdx.x * 256 + threadIdx.x;   // 32768 = 64*512
  const int b = i >> 9, d = i & 511;
  float s = 0.f;
  #pragma unroll
  for (int nc = 0; nc < 16; ++nc) s += cpart[((size_t)(b * 16 + nc)) * DD + d];
  ctx[i] = s;
}

extern "C" void kernel_launch(void* const* d_in, const int* in_sizes, int n_in,
                              void* d_out, int out_size, void* d_ws, size_t ws_size,
                              hipStream_t stream) {
  const float* h    = (const float*)d_in[0];
  const float* enc  = (const float*)d_in[1];
  const int*   mask = (const int*)d_in[2];
  const float* Wh   = (const float*)d_in[3];
  const float* We   = (const float*)d_in[4];
  const float* v    = (const float*)d_in[5];

  float* out   = (float*)d_out;
  float* ctx   = out;                 // (B, D)
  float* alpha = out + BB * DD;       // (B, N)

  char* w = (char*)d_ws;
  unsigned short* web = (unsigned short*)w;                 // 512 KB
  float* ph     = (float*)(w + (size_t)AA * DD * 2);        // 128 KB
  float* scores = ph + BB * AA;                             // 512 KB
  float* cpart  = scores + BB * NN;                         // 2 MB

  we_cast_kernel<<<(AA * DD / 8 + 255) / 256, 256, 0, stream>>>(We, web);
  proj_h_kernel<<<dim3(BB, 2), 256, 0, stream>>>(h, Wh, ph);
  scores_reg<<<(BB * NN) / 256, 256, 0, stream>>>(enc, web, ph, v, scores);
  softmax_kernel<<<BB, 256, 0, stream>>>(scores, mask, alpha);
  context_part<<<dim3(BB, 16), 128, 0, stream>>>(enc, alpha, cpart);
  context_reduce<<<(BB * DD) / 256, 256, 0, stream>>>(cpart, ctx);
  (void)in_sizes; (void)n_in; (void)out_size; (void)ws_size;
}

// Round 4
// 547.601 us; speedup vs baseline: 1.1483x; 1.1483x over previous
//
#include <hip/hip_runtime.h>
#include <hip/hip_bf16.h>
#include <cstdint>
#include <cstddef>

#define NEG_INF (-1.0e9f)

typedef __attribute__((ext_vector_type(8))) short bf16x8;
typedef __attribute__((ext_vector_type(8))) unsigned short u16x8;
typedef __attribute__((ext_vector_type(4))) float f32x4;

constexpr int BB = 64;     // batch
constexpr int NN = 2048;   // seq len
constexpr int HH = 512;    // h dim
constexpr int DD = 512;    // enc dim (GEMM K)
constexpr int AA = 512;    // attention dim (GEMM N)

constexpr int LDA = 520;   // padded LDS row stride (ushorts): 1040 B, breaks 1024-B bank wrap

__device__ __forceinline__ unsigned short f2bf(float x) {
  unsigned int u = __float_as_uint(x);
  return (unsigned short)((u + 0x8000u) >> 16);
}

__device__ __forceinline__ float fast_rcp(float x) {
#if __has_builtin(__builtin_amdgcn_rcpf)
  return __builtin_amdgcn_rcpf(x);
#else
  return 1.f / x;
#endif
}

__device__ __forceinline__ float fast_tanh(float x) {
  float e = __expf(2.f * fabsf(x));
  float t = 1.f - 2.f * fast_rcp(e + 1.f);
  return copysignf(t, x);
}

// 8 fp32 -> bf16x8 via packed HW cvt
__device__ __forceinline__ bf16x8 pack8(const float4& lo, const float4& hi) {
  __hip_bfloat162 a = __float22bfloat162_rn(float2{lo.x, lo.y});
  __hip_bfloat162 b = __float22bfloat162_rn(float2{lo.z, lo.w});
  __hip_bfloat162 c = __float22bfloat162_rn(float2{hi.x, hi.y});
  __hip_bfloat162 d = __float22bfloat162_rn(float2{hi.z, hi.w});
  union { unsigned int w[4]; bf16x8 v; } u;
  __builtin_memcpy(&u.w[0], &a, 4);
  __builtin_memcpy(&u.w[1], &b, 4);
  __builtin_memcpy(&u.w[2], &c, 4);
  __builtin_memcpy(&u.w[3], &d, 4);
  return u.v;
}

// -------- We -> bf16 (512 KB ws) --------
__global__ __launch_bounds__(256)
void we_cast_kernel(const float* __restrict__ We, unsigned short* __restrict__ web) {
  int i = (blockIdx.x * 256 + threadIdx.x) * 8;
  if (i >= AA * DD) return;
  float4 s0 = *(const float4*)(We + i);
  float4 s1 = *(const float4*)(We + i + 4);
  *(bf16x8*)(web + i) = pack8(s0, s1);
}

// -------- proj_h --------
__global__ __launch_bounds__(256)
void proj_h_kernel(const float* __restrict__ h, const float* __restrict__ Wh,
                   float* __restrict__ ph) {
  __shared__ float hL[HH];
  const int b = blockIdx.x;
  hL[threadIdx.x]       = h[b * HH + threadIdx.x];
  hL[threadIdx.x + 256] = h[b * HH + threadIdx.x + 256];
  __syncthreads();
  const int a = blockIdx.y * 256 + threadIdx.x;
  const float4* wr = (const float4*)(Wh + (size_t)a * HH);
  float acc = 0.f;
  #pragma unroll 4
  for (int j = 0; j < HH / 4; ++j) {
    float4 w = wr[j];
    acc += w.x * hL[4*j] + w.y * hL[4*j+1] + w.z * hL[4*j+2] + w.w * hL[4*j+3];
  }
  ph[b * AA + a] = acc;
}

// -------- fused scores: full-K A-tile in LDS, barrier-free K-loop --------
// Block = 64 rows, 4 waves. Wave w computes all 64 rows x cols [w*128, w*128+128).
// A-frags from LDS (staged once, padded); B-frags 16 B/lane direct from bf16 web (L2-hot).
__global__ __launch_bounds__(256, 2)
void scores_fullk(const float* __restrict__ enc, const unsigned short* __restrict__ web,
                  const float* __restrict__ ph, const float* __restrict__ vvec,
                  float* __restrict__ scores) {
  __shared__ unsigned short As[64 * LDA];   // 66,560 B
  __shared__ float sred[4][64];

  const int tid  = threadIdx.x;
  const int lane = tid & 63;
  const int wid  = tid >> 6;
  const int c    = lane & 15;
  const int quad = lane >> 4;

  const int r0 = blockIdx.x * 64;
  const int b  = r0 >> 11;                  // 64 | 2048, tiles never cross batch

  // ---- stage A: 64 rows x 512 k, fp32 -> bf16, one pass, fully coalesced ----
  {
    const float* src = enc + (size_t)r0 * DD;
    #pragma unroll
    for (int s = 0; s < 16; ++s) {
      const int flat = s * 2048 + tid * 8;  // block covers 2048 contiguous floats/iter
      float4 lo = *(const float4*)(src + flat);
      float4 hi = *(const float4*)(src + flat + 4);
      const int row = flat >> 9, col = flat & 511;
      *(bf16x8*)&As[row * LDA + col] = pack8(lo, hi);
    }
  }
  __syncthreads();                          // the only barrier before the epilogue

  // per-lane fragment bases
  const unsigned short* bBase = web + ((size_t)(wid * 128 + c)) * DD + quad * 8;
  const unsigned short* aBase = &As[c * LDA + quad * 8];

  float pp[8], vv[8];
  #pragma unroll
  for (int j = 0; j < 8; ++j) {
    const int col = wid * 128 + j * 16 + c;
    pp[j] = ph[b * AA + col];
    vv[j] = vvec[col];
  }

  f32x4 acc[4][8];
  #pragma unroll
  for (int i = 0; i < 4; ++i)
    #pragma unroll
    for (int j = 0; j < 8; ++j)
      acc[i][j] = (f32x4){0.f, 0.f, 0.f, 0.f};

  #pragma unroll 2
  for (int k0 = 0; k0 < DD; k0 += 32) {
    bf16x8 bfr[8];
    #pragma unroll
    for (int j = 0; j < 8; ++j)
      bfr[j] = *(const bf16x8*)(bBase + (size_t)(j * 16) * DD + k0);
    bf16x8 af[4];
    #pragma unroll
    for (int i = 0; i < 4; ++i)
      af[i] = *(const bf16x8*)(aBase + i * 16 * LDA + k0);
    #pragma unroll
    for (int i = 0; i < 4; ++i)
      #pragma unroll
      for (int j = 0; j < 8; ++j)
        acc[i][j] = __builtin_amdgcn_mfma_f32_16x16x32_bf16(af[i], bfr[j], acc[i][j], 0, 0, 0);
  }

  // epilogue: per-row partial = sum_cols v*tanh(acc+ph); C/D: row=quad*4+r, col=c
  #pragma unroll
  for (int i = 0; i < 4; ++i) {
    #pragma unroll
    for (int r = 0; r < 4; ++r) {
      float p = 0.f;
      #pragma unroll
      for (int j = 0; j < 8; ++j)
        p += vv[j] * fast_tanh(acc[i][j][r] + pp[j]);
      p += __shfl_xor(p, 1, 64);
      p += __shfl_xor(p, 2, 64);
      p += __shfl_xor(p, 4, 64);
      p += __shfl_xor(p, 8, 64);
      if (c == 0) sred[wid][i * 16 + quad * 4 + r] = p;
    }
  }
  __syncthreads();
  if (tid < 64)
    scores[r0 + tid] = sred[0][tid] + sred[1][tid] + sred[2][tid] + sred[3][tid];
}

// -------- masked softmax over N per batch; alpha to d_out --------
__global__ __launch_bounds__(256)
void softmax_kernel(const float* __restrict__ scores, const int* __restrict__ mask,
                    float* __restrict__ alpha) {
  const int b = blockIdx.x, tid = threadIdx.x;
  const int base = b * NN;
  float vals[8];
  float mx = -3.4e38f;
  #pragma unroll
  for (int i = 0; i < 8; ++i) {
    int n = tid + 256 * i;
    float s = scores[base + n];
    if (mask[base + n] == 0) s = NEG_INF;
    vals[i] = s;
    mx = fmaxf(mx, s);
  }
  #pragma unroll
  for (int o = 32; o; o >>= 1) mx = fmaxf(mx, __shfl_xor(mx, o, 64));
  __shared__ float w4[4];
  if ((tid & 63) == 0) w4[tid >> 6] = mx;
  __syncthreads();
  mx = fmaxf(fmaxf(w4[0], w4[1]), fmaxf(w4[2], w4[3]));
  float sum = 0.f;
  #pragma unroll
  for (int i = 0; i < 8; ++i) { vals[i] = __expf(vals[i] - mx); sum += vals[i]; }
  #pragma unroll
  for (int o = 32; o; o >>= 1) sum += __shfl_xor(sum, o, 64);
  __shared__ float s4[4];
  if ((tid & 63) == 0) s4[tid >> 6] = sum;
  __syncthreads();
  sum = s4[0] + s4[1] + s4[2] + s4[3];
  float inv = 1.f / sum;
  #pragma unroll
  for (int i = 0; i < 8; ++i) alpha[base + tid + 256 * i] = vals[i] * inv;
}

// -------- context partials: 2048 blocks (64-row chunks), 2 accumulators --------
__global__ __launch_bounds__(128)
void context_part(const float* __restrict__ enc, const float* __restrict__ alpha,
                  float* __restrict__ cpart) {
  const int b  = blockIdx.x;
  const int nc = blockIdx.y;     // 32 chunks of 64 n
  const int t  = threadIdx.x;
  __shared__ float aL[64];
  if (t < 64) aL[t] = alpha[b * NN + nc * 64 + t];
  __syncthreads();
  const float* ep = enc + ((size_t)b * NN + nc * 64) * DD + t * 4;
  float4 a0 = {0.f, 0.f, 0.f, 0.f}, a1 = {0.f, 0.f, 0.f, 0.f};
  #pragma unroll 4
  for (int n = 0; n < 64; n += 2) {
    float4 e0 = *(const float4*)(ep + (size_t)n * DD);
    float4 e1 = *(const float4*)(ep + (size_t)(n + 1) * DD);
    float s0 = aL[n], s1 = aL[n + 1];
    a0.x += s0 * e0.x; a0.y += s0 * e0.y; a0.z += s0 * e0.z; a0.w += s0 * e0.w;
    a1.x += s1 * e1.x; a1.y += s1 * e1.y; a1.z += s1 * e1.z; a1.w += s1 * e1.w;
  }
  a0.x += a1.x; a0.y += a1.y; a0.z += a1.z; a0.w += a1.w;
  *(float4*)(cpart + ((size_t)(b * 32 + nc)) * DD + t * 4) = a0;
}

__global__ __launch_bounds__(256)
void context_reduce(const float* __restrict__ cpart, float* __restrict__ ctx) {
  const int i = blockIdx.x * 256 + threadIdx.x;   // 32768 = 64*512
  const int b = i >> 9, d = i & 511;
  float s = 0.f;
  #pragma unroll
  for (int nc = 0; nc < 32; ++nc) s += cpart[((size_t)(b * 32 + nc)) * DD + d];
  ctx[i] = s;
}

extern "C" void kernel_launch(void* const* d_in, const int* in_sizes, int n_in,
                              void* d_out, int out_size, void* d_ws, size_t ws_size,
                              hipStream_t stream) {
  const float* h    = (const float*)d_in[0];
  const float* enc  = (const float*)d_in[1];
  const int*   mask = (const int*)d_in[2];
  const float* Wh   = (const float*)d_in[3];
  const float* We   = (const float*)d_in[4];
  const float* v    = (const float*)d_in[5];

  float* out   = (float*)d_out;
  float* ctx   = out;                 // (B, D)
  float* alpha = out + BB * DD;       // (B, N)

  char* w = (char*)d_ws;
  unsigned short* web = (unsigned short*)w;                 // 512 KB
  float* ph     = (float*)(w + (size_t)AA * DD * 2);        // 128 KB
  float* scores = ph + BB * AA;                             // 512 KB
  float* cpart  = scores + BB * NN;                         // 4 MB

  we_cast_kernel<<<(AA * DD / 8 + 255) / 256, 256, 0, stream>>>(We, web);
  proj_h_kernel<<<dim3(BB, 2), 256, 0, stream>>>(h, Wh, ph);
  scores_fullk<<<(BB * NN) / 64, 256, 0, stream>>>(enc, web, ph, v, scores);
  softmax_kernel<<<BB, 256, 0, stream>>>(scores, mask, alpha);
  context_part<<<dim3(BB, 32), 128, 0, stream>>>(enc, alpha, cpart);
  context_reduce<<<(BB * DD) / 256, 256, 0, stream>>>(cpart, ctx);
  (void)in_sizes; (void)n_in; (void)out_size; (void)ws_size;
}